// Round 7
// baseline (7305.917 us; speedup 1.0000x reference)
//
#include <hip/hip_runtime.h>
#include <math.h>

#define BB 4096
#define TT 5
#define KK 4
#define NLANES 12
#define GH 64
#define GO 32
#define GAT_TOT 256
#define SAGE_H 64
#define GRU_H 32

typedef __attribute__((ext_vector_type(8))) short short8v;
typedef __attribute__((ext_vector_type(8))) unsigned short ushort8v;
typedef __attribute__((ext_vector_type(4))) unsigned short ushort4v;
typedef __attribute__((ext_vector_type(4))) float f32x4;

__device__ __forceinline__ unsigned short f2bf(float x) {
    unsigned u = __float_as_uint(x);
    u += 0x7fffu + ((u >> 16) & 1u);
    return (unsigned short)(u >> 16);
}
__device__ __forceinline__ float bf2f(unsigned short b) {
    return __uint_as_float(((unsigned)b) << 16);
}

// ---------------------------------------------------------------------------
// Setup: wt bf16 [288][64]:
//   cols 0..255   : W^T (col c = g*128+hh*32+o, value W_g[hh][k][o])
//   cols 256..271 : hi(W_gh @ a)  (l15<8: src gh=l15; l15>=8: dst gh=l15-8)
//   cols 272..287 : bf16 residual (lo) of the same
// ---------------------------------------------------------------------------
__global__ void setup_kernel(const float* __restrict__ coopW, const float* __restrict__ confW,
                             const float* __restrict__ coopS, const float* __restrict__ coopD,
                             const float* __restrict__ confS, const float* __restrict__ confD,
                             unsigned short* __restrict__ wt) {
    const int tnum = threadIdx.x;   // 256 threads
    {
        int c = tnum;
        int g = c >> 7, hh = (c >> 5) & 3, o = c & 31;
        const float* W = (g ? confW : coopW) + hh * (GH * GO) + o;
        for (int k = 0; k < GH; ++k)
            wt[c * GH + k] = f2bf(W[k * GO]);
    }
    if (tnum < 16) {
        int q = tnum;
        int half = q >> 3, ghx = q & 7;
        int g = ghx >> 2, hh = ghx & 3;
        const float* W = (g ? confW : coopW) + hh * (GH * GO);
        const float* a = (half ? (g ? confD : coopD) : (g ? confS : coopS)) + hh * GO;
        for (int k = 0; k < GH; ++k) {
            float s = 0.f;
            for (int o2 = 0; o2 < GO; ++o2) s += W[k * GO + o2] * a[o2];
            unsigned short hi = f2bf(s);
            wt[(256 + q) * GH + k] = hi;
            wt[(272 + q) * GH + k] = f2bf(s - bf2f(hi));
        }
    }
}

// ---------------------------------------------------------------------------
// Kernel A: per (b,t) block. Round-4 skeleton (transient A-frag loads, low
// liveness) + separate mini-GEMM phase for attention scalars + array-free
// parallel softmax + float4 pool.
// ---------------------------------------------------------------------------
__global__ __launch_bounds__(256, 3) void gat_sage_kernel(
    const float* __restrict__ selfF, const float* __restrict__ nbF,
    const float* __restrict__ mask,
    const float* __restrict__ projW, const float* __restrict__ projB,
    const float* __restrict__ projG, const float* __restrict__ projBt,
    const unsigned short* __restrict__ wt,
    const float* __restrict__ sageW, const float* __restrict__ sageB,
    float* __restrict__ hsage, float* __restrict__ embLast)
{
    __shared__ __align__(16) float s_x[256];
    __shared__ __align__(16) unsigned short s_hb[64 * 64];   // 8 KB, lives P1..P3
    __shared__ __align__(16) char sA[32768];                 // WhT | s_att | s_in/s_part
    __shared__ float s_sdh[2][8][60];
    __shared__ float s_sdl[2][8][60];

    unsigned short* WhT = (unsigned short*)sA;                          // [256][64] bf16 swz
    float (*s_att)[8][NLANES][16] = (float (*)[8][NLANES][16])sA;       // [5][8][12][16]
    float* s_in = (float*)sA;                                           // [512]
    float (*s_part)[SAGE_H] = (float (*)[SAGE_H])(sA + 2048);           // [4][64]

    const int bid = blockIdx.x;          // b*T + t
    const int b = bid / TT, t = bid % TT;
    const int tid = threadIdx.x;

    const int wv = tid >> 6, f = tid & 63;    // wave, lane
    const int l15 = f & 15, g4 = f >> 4;
    const int gh = tid >> 5;                  // pool: col = tid

    // ---- stage inputs ----
    if (tid < 60) {
        int inst = tid / 12, j = tid % 12;
        const float* xp = (inst == 0)
            ? (selfF + (size_t)bid * 48)
            : (nbF + (size_t)((b * KK + (inst - 1)) * TT + t) * 48);
        ((float4*)s_x)[tid] = ((const float4*)xp)[j];
    }
    const float m0 = mask[b * KK + 0], m1 = mask[b * KK + 1];
    const float m2 = mask[b * KK + 2], m3 = mask[b * KK + 3];

    // proj row in registers (lane = feature f)
    const float pw0 = projW[0 * GH + f], pw1 = projW[1 * GH + f];
    const float pw2 = projW[2 * GH + f], pw3 = projW[3 * GH + f];
    const float pb = projB[f], pg = projG[f], pbt = projBt[f];
    __syncthreads();

    // ---- P1: proj + LN + relu -> s_hb (bf16, frag-swizzled); rows 60..63 zero
    #pragma unroll
    for (int i = 0; i < 15; ++i) {
        const int r = wv + i * 4;
        float v = fmaf(s_x[r * 4 + 0], pw0, fmaf(s_x[r * 4 + 1], pw1,
                  fmaf(s_x[r * 4 + 2], pw2, fmaf(s_x[r * 4 + 3], pw3, pb))));
        float s1 = v, s2 = v * v;
        #pragma unroll
        for (int m = 1; m < 64; m <<= 1) {
            s1 += __shfl_xor(s1, m);
            s2 += __shfl_xor(s2, m);
        }
        float mean = s1 * (1.f / 64.f);
        float var  = s2 * (1.f / 64.f) - mean * mean;
        float nv = (v - mean) * rsqrtf(var + 1e-5f) * pg + pbt;
        nv = fmaxf(nv, 0.f);
        s_hb[r * 64 + (((f >> 3) ^ (r & 7)) << 3) + (f & 7)] = f2bf(nv);
    }
    {   // zero rows 60..63 (wave wv -> row 60+wv)
        const int r = 60 + wv;
        s_hb[r * 64 + (((f >> 3) ^ (r & 7)) << 3) + (f & 7)] = 0;
    }
    __syncthreads();

    // ---- P2: base GEMM [64x64]@[64x256]; A-frags re-read per kt (transient) --
    {
        f32x4 c[4][4];
        #pragma unroll
        for (int mt = 0; mt < 4; ++mt)
            #pragma unroll
            for (int nt = 0; nt < 4; ++nt)
                c[mt][nt] = (f32x4){0.f, 0.f, 0.f, 0.f};

        #pragma unroll
        for (int kt = 0; kt < 2; ++kt) {
            const int kc = kt * 4 + g4;
            short8v a[4], bfr[4];
            #pragma unroll
            for (int mt = 0; mt < 4; ++mt) {
                const int r = mt * 16 + l15;
                a[mt] = *(const short8v*)&s_hb[r * 64 + ((kc ^ (r & 7)) << 3)];
            }
            #pragma unroll
            for (int nt = 0; nt < 4; ++nt)
                bfr[nt] = *(const short8v*)&wt[(wv * 64 + nt * 16 + l15) * GH + kc * 8];
            #pragma unroll
            for (int mt = 0; mt < 4; ++mt)
                #pragma unroll
                for (int nt = 0; nt < 4; ++nt)
                    c[mt][nt] = __builtin_amdgcn_mfma_f32_16x16x32_bf16(
                        a[mt], bfr[nt], c[mt][nt], 0, 0, 0);
        }

        // pack C -> WhT bf16 [col][64 rows] (swizzled); c dies here
        #pragma unroll
        for (int mt = 0; mt < 4; ++mt) {
            #pragma unroll
            for (int nt = 0; nt < 4; ++nt) {
                const int cc = wv * 64 + nt * 16 + l15;
                const int rb = mt * 16 + g4 * 4;
                ushort4v p;
                p.x = f2bf(c[mt][nt][0]); p.y = f2bf(c[mt][nt][1]);
                p.z = f2bf(c[mt][nt][2]); p.w = f2bf(c[mt][nt][3]);
                *(ushort4v*)&WhT[cc * 64 + (((rb >> 3) ^ (cc & 7)) << 3) + (rb & 7)] = p;
            }
        }
    }

    // ---- P3: mini-GEMM for attention scalars (wave0=hi, wave1=lo cols) ----
    if (wv < 2) {
        f32x4 c2[4];
        #pragma unroll
        for (int mt = 0; mt < 4; ++mt) c2[mt] = (f32x4){0.f, 0.f, 0.f, 0.f};
        #pragma unroll
        for (int kt = 0; kt < 2; ++kt) {
            const int kc = kt * 4 + g4;
            short8v bq = *(const short8v*)&wt[(256 + wv * 16 + l15) * GH + kc * 8];
            #pragma unroll
            for (int mt = 0; mt < 4; ++mt) {
                const int r = mt * 16 + l15;
                short8v a = *(const short8v*)&s_hb[r * 64 + ((kc ^ (r & 7)) << 3)];
                c2[mt] = __builtin_amdgcn_mfma_f32_16x16x32_bf16(a, bq, c2[mt], 0, 0, 0);
            }
        }
        const int half = l15 >> 3, ghx = l15 & 7;
        float (*dst)[8][60] = (wv == 0) ? s_sdh : s_sdl;
        #pragma unroll
        for (int mt = 0; mt < 4; ++mt) {
            #pragma unroll
            for (int r = 0; r < 4; ++r) {
                const int rb = mt * 16 + g4 * 4 + r;
                if (rb < 60) dst[half][ghx][rb] = c2[mt][r];
            }
        }
    }
    __syncthreads();

    // ---- P4: readback acc[r] = Wh[r][col=tid] ----
    float acc[60];
    {
        const int cs = tid & 7;
        #pragma unroll
        for (int ch = 0; ch < 8; ++ch) {
            ushort8v v = *(const ushort8v*)&WhT[tid * 64 + ((ch ^ cs) << 3)];
            #pragma unroll
            for (int j = 0; j < 8; ++j) {
                const int r = ch * 8 + j;
                if (r < 60) acc[r] = bf2f(v[j]);
            }
        }
    }
    __syncthreads();   // WhT dead; s_att region live from here

    // ---- P5: masked softmax, 480 tasks over 2 rounds, array-free online ----
    #pragma unroll
    for (int round = 0; round < 2; ++round) {
        const int task = tid + round * 256;
        if (task < 480) {
            const int inst = task / 96;
            const int rem = task - inst * 96;
            const int gh2 = rem / 12, n2 = rem - (rem / 12) * 12;
            const int g2 = gh2 >> 2;
            const int an = n2 / 3;
            const float sn = s_sdh[0][gh2][inst * 12 + n2] + s_sdl[0][gh2][inst * 12 + n2];
            float mx = -1e30f, sum = 0.f;
            #pragma unroll
            for (int mm = 0; mm < NLANES; ++mm) {
                int am = mm / 3;
                bool valid = (g2 == 0) ? (am == an) : (am != an || mm == n2);
                if (valid) {
                    float ev = sn + s_sdh[1][gh2][inst * 12 + mm] + s_sdl[1][gh2][inst * 12 + mm];
                    ev = ev > 0.f ? ev : 0.2f * ev;
                    float nmx = fmaxf(mx, ev);
                    sum = sum * __expf(mx - nmx) + __expf(ev - nmx);
                    mx = nmx;
                }
            }
            const float inv = 1.f / sum;
            #pragma unroll
            for (int mm = 0; mm < NLANES; ++mm) {
                int am = mm / 3;
                bool valid = (g2 == 0) ? (am == an) : (am != an || mm == n2);
                float ev = sn + s_sdh[1][gh2][inst * 12 + mm] + s_sdl[1][gh2][inst * 12 + mm];
                ev = ev > 0.f ? ev : 0.2f * ev;
                s_att[inst][gh2][n2][mm] = valid ? __expf(ev - mx) * inv : 0.f;
            }
        }
    }
    __syncthreads();

    // ---- P6: pool = elu(att @ Wh) mean over lanes ----
    float pooled0 = 0.f, paggr = 0.f;
    #pragma unroll
    for (int inst = 0; inst < 5; ++inst) {
        float pooled = 0.f;
        #pragma unroll
        for (int n = 0; n < NLANES; ++n) {
            const float4* arow = (const float4*)s_att[inst][gh][n];
            float4 a0 = arow[0], a1 = arow[1], a2 = arow[2];
            float v = a0.x * acc[inst * 12 + 0] + a0.y * acc[inst * 12 + 1]
                    + a0.z * acc[inst * 12 + 2] + a0.w * acc[inst * 12 + 3]
                    + a1.x * acc[inst * 12 + 4] + a1.y * acc[inst * 12 + 5]
                    + a1.z * acc[inst * 12 + 6] + a1.w * acc[inst * 12 + 7]
                    + a2.x * acc[inst * 12 + 8] + a2.y * acc[inst * 12 + 9]
                    + a2.z * acc[inst * 12 + 10] + a2.w * acc[inst * 12 + 11];
            v = v > 0.f ? v : (__expf(v) - 1.f);
            pooled += v;
        }
        pooled *= (1.f / 12.f);
        if (inst == 0) pooled0 = pooled;
        else paggr += (inst == 1 ? m0 : inst == 2 ? m1 : inst == 3 ? m2 : m3) * pooled;
    }
    if (t == TT - 1) embLast[(size_t)b * GAT_TOT + tid] = pooled0;
    __syncthreads();   // att dead

    // ---- P7: concat -> s_in; central-node SAGE row ----
    {
        const float inv = 1.f / fmaxf(m0 + m1 + m2 + m3, 1.f);
        s_in[tid] = pooled0;
        s_in[GAT_TOT + tid] = paggr * inv;
    }
    __syncthreads();
    {
        const int j = tid & 63, q = tid >> 6;
        const float4* si4 = (const float4*)s_in;
        float v = 0.f;
        #pragma unroll 8
        for (int cq = q * 32; cq < q * 32 + 32; ++cq) {
            float4 s4 = si4[cq];
            const float* Wp = sageW + (cq * 4) * SAGE_H + j;
            v += s4.x * Wp[0] + s4.y * Wp[SAGE_H] + s4.z * Wp[2 * SAGE_H] + s4.w * Wp[3 * SAGE_H];
        }
        s_part[q][j] = v;
    }
    __syncthreads();
    if (tid < SAGE_H) {
        float v = sageB[tid] + s_part[0][tid] + s_part[1][tid]
                + s_part[2][tid] + s_part[3][tid];
        hsage[(size_t)bid * SAGE_H + tid] = fmaxf(v, 0.f);
    }
}

// ---------------------------------------------------------------------------
// Kernel B: per-b block, 256 threads (unchanged).
// ---------------------------------------------------------------------------
__global__ __launch_bounds__(256) void gru_head_kernel(
    const float* __restrict__ hsage, const float* __restrict__ embLast,
    const float* __restrict__ gfWx, const float* __restrict__ gfWh,
    const float* __restrict__ gfbx, const float* __restrict__ gfbh,
    const float* __restrict__ gbWx, const float* __restrict__ gbWh,
    const float* __restrict__ gbbx, const float* __restrict__ gbbh,
    const float* __restrict__ pW1, const float* __restrict__ pb1,
    const float* __restrict__ pg1, const float* __restrict__ pbt1,
    const float* __restrict__ pW2, const float* __restrict__ pb2,
    const float* __restrict__ pg2, const float* __restrict__ pbt2,
    const float* __restrict__ pWo, const float* __restrict__ pbo,
    const float* __restrict__ vW1, const float* __restrict__ vb1,
    const float* __restrict__ vg1, const float* __restrict__ vbt1,
    const float* __restrict__ vW2, const float* __restrict__ vb2,
    const float* __restrict__ vg2, const float* __restrict__ vbt2,
    const float* __restrict__ vWo, const float* __restrict__ vbo,
    float* __restrict__ dout)
{
    __shared__ float s_seq[TT * SAGE_H];
    __shared__ float s_gx[2][TT][96];
    __shared__ float s_hh[2][GRU_H];
    __shared__ float s_joint[320];
    __shared__ float s_h1[128];
    __shared__ float s_h2[64];
    __shared__ float s_p1[2][128];
    __shared__ float s_p2[4][64];
    __shared__ float s_red[4];

    const int b = blockIdx.x, tid = threadIdx.x;

    for (int i = tid; i < TT * SAGE_H; i += 256) s_seq[i] = hsage[(size_t)b * TT * SAGE_H + i];
    s_joint[tid] = embLast[(size_t)b * GAT_TOT + tid];
    if (tid < 64) s_hh[tid >> 5][tid & 31] = 0.f;
    __syncthreads();

    for (int task = tid; task < 960; task += 256) {
        int dir = task >= 480;
        int rem = task - dir * 480;
        int t5 = rem / 96, j = rem - t5 * 96;
        const float* Wx = dir ? gbWx : gfWx;
        const float* bx = dir ? gbbx : gfbx;
        const float* x = &s_seq[t5 * SAGE_H];
        float v = bx[j];
        for (int f2 = 0; f2 < SAGE_H; ++f2) v += x[f2] * Wx[f2 * 96 + j];
        s_gx[dir][t5][j] = v;
    }
    __syncthreads();

    for (int s = 0; s < TT; ++s) {
        float hnew = 0.f;
        if (tid < 64) {
            int dir = tid >> 5, j = tid & 31;
            int t5 = dir ? (TT - 1 - s) : s;
            const float* Wh = dir ? gbWh : gfWh;
            const float* bh = dir ? gbbh : gfbh;
            const float* h = s_hh[dir];
            float hr = bh[j], hz = bh[32 + j], hn = bh[64 + j];
            for (int k = 0; k < GRU_H; ++k) {
                float hv = h[k];
                hr += hv * Wh[k * 96 + j];
                hz += hv * Wh[k * 96 + 32 + j];
                hn += hv * Wh[k * 96 + 64 + j];
            }
            float xr = s_gx[dir][t5][j], xz = s_gx[dir][t5][32 + j], xn = s_gx[dir][t5][64 + j];
            float r = 1.f / (1.f + __expf(-(xr + hr)));
            float z = 1.f / (1.f + __expf(-(xz + hz)));
            float nn = tanhf(xn + r * hn);
            hnew = (1.f - z) * nn + z * h[j];
        }
        __syncthreads();
        if (tid < 64) s_hh[tid >> 5][tid & 31] = hnew;
        __syncthreads();
    }
    if (tid < 64) s_joint[GAT_TOT + tid] = s_hh[tid >> 5][tid & 31];
    __syncthreads();

    for (int hd = 0; hd < 2; ++hd) {
        const float* W1 = hd ? vW1 : pW1;  const float* b1 = hd ? vb1 : pb1;
        const float* g1 = hd ? vg1 : pg1;  const float* bt1 = hd ? vbt1 : pbt1;
        const float* W2 = hd ? vW2 : pW2;  const float* b2 = hd ? vb2 : pb2;
        const float* g2 = hd ? vg2 : pg2;  const float* bt2 = hd ? vbt2 : pbt2;
        const float* Wo = hd ? vWo : pWo;  const float* bo = hd ? vbo : pbo;

        {
            int j = tid & 127, hf = tid >> 7;
            float v = (hf == 0) ? b1[j] : 0.f;
            for (int c2 = hf * 160; c2 < hf * 160 + 160; ++c2)
                v += s_joint[c2] * W1[c2 * 128 + j];
            s_p1[hf][j] = v;
        }
        __syncthreads();
        if (tid < 128) {
            float vv = s_p1[0][tid] + s_p1[1][tid];
            float q1 = vv, q2 = vv * vv;
            #pragma unroll
            for (int m = 1; m < 64; m <<= 1) { q1 += __shfl_xor(q1, m); q2 += __shfl_xor(q2, m); }
            if ((tid & 63) == 0) { s_red[(tid >> 6) * 2] = q1; s_red[(tid >> 6) * 2 + 1] = q2; }
        }
        __syncthreads();
        if (tid < 128) {
            float sum1 = s_red[0] + s_red[2], sum2 = s_red[1] + s_red[3];
            float mean = sum1 * (1.f / 128.f);
            float var = sum2 * (1.f / 128.f) - mean * mean;
            float vv = s_p1[0][tid] + s_p1[1][tid];
            s_h1[tid] = fmaxf((vv - mean) * rsqrtf(var + 1e-5f) * g1[tid] + bt1[tid], 0.f);
        }
        __syncthreads();

        {
            int j = tid & 63, q = tid >> 6;
            float v = (q == 0) ? b2[j] : 0.f;
            for (int c2 = q * 32; c2 < q * 32 + 32; ++c2)
                v += s_h1[c2] * W2[c2 * 64 + j];
            s_p2[q][j] = v;
        }
        __syncthreads();
        if (tid < 64) {
            float vv = s_p2[0][tid] + s_p2[1][tid] + s_p2[2][tid] + s_p2[3][tid];
            float q1 = vv, q2 = vv * vv;
            #pragma unroll
            for (int m = 1; m < 64; m <<= 1) { q1 += __shfl_xor(q1, m); q2 += __shfl_xor(q2, m); }
            float mean = q1 * (1.f / 64.f);
            float var = q2 * (1.f / 64.f) - mean * mean;
            s_h2[tid] = fmaxf((vv - mean) * rsqrtf(var + 1e-5f) * g2[tid] + bt2[tid], 0.f);
        }
        __syncthreads();

        if (hd == 0) {
            if (tid < 8) {
                float v3 = bo[tid];
                for (int c2 = 0; c2 < 64; ++c2) v3 += s_h2[c2] * Wo[c2 * 8 + tid];
                dout[(size_t)b * 8 + tid] = v3;
            }
        } else {
            if (tid == 0) {
                float v3 = bo[0];
                for (int c2 = 0; c2 < 64; ++c2) v3 += s_h2[c2] * Wo[c2];
                dout[(size_t)BB * 8 + b] = v3;
            }
        }
        __syncthreads();
    }
}

extern "C" void kernel_launch(void* const* d_in, const int* in_sizes, int n_in,
                              void* d_out, int out_size, void* d_ws, size_t ws_size,
                              hipStream_t stream) {
    (void)in_sizes; (void)n_in; (void)out_size; (void)ws_size;
    const float* selfF  = (const float*)d_in[0];
    const float* nbF    = (const float*)d_in[1];
    const float* mask   = (const float*)d_in[2];
    const float* projW  = (const float*)d_in[3];
    const float* projB  = (const float*)d_in[4];
    const float* projG  = (const float*)d_in[5];
    const float* projBt = (const float*)d_in[6];
    const float* coopW  = (const float*)d_in[7];
    const float* coopS  = (const float*)d_in[8];
    const float* coopD  = (const float*)d_in[9];
    const float* confW  = (const float*)d_in[10];
    const float* confS  = (const float*)d_in[11];
    const float* confD  = (const float*)d_in[12];
    const float* sageW  = (const float*)d_in[13];
    const float* sageB  = (const float*)d_in[14];
    const float* gfWx = (const float*)d_in[15];
    const float* gfWh = (const float*)d_in[16];
    const float* gfbx = (const float*)d_in[17];
    const float* gfbh = (const float*)d_in[18];
    const float* gbWx = (const float*)d_in[19];
    const float* gbWh = (const float*)d_in[20];
    const float* gbbx = (const float*)d_in[21];
    const float* gbbh = (const float*)d_in[22];
    const float* pW1  = (const float*)d_in[23];
    const float* pb1  = (const float*)d_in[24];
    const float* pg1  = (const float*)d_in[25];
    const float* pbt1 = (const float*)d_in[26];
    const float* pW2  = (const float*)d_in[27];
    const float* pb2  = (const float*)d_in[28];
    const float* pg2  = (const float*)d_in[29];
    const float* pbt2 = (const float*)d_in[30];
    const float* pWo  = (const float*)d_in[31];
    const float* pbo  = (const float*)d_in[32];
    const float* vW1  = (const float*)d_in[33];
    const float* vb1  = (const float*)d_in[34];
    const float* vg1  = (const float*)d_in[35];
    const float* vbt1 = (const float*)d_in[36];
    const float* vW2  = (const float*)d_in[37];
    const float* vb2  = (const float*)d_in[38];
    const float* vg2  = (const float*)d_in[39];
    const float* vbt2 = (const float*)d_in[40];
    const float* vWo  = (const float*)d_in[41];
    const float* vbo  = (const float*)d_in[42];

    float* hsage   = (float*)d_ws;                                    // B*T*64 f32
    float* embLast = hsage + (size_t)BB * TT * SAGE_H;                // B*256 f32
    unsigned short* wt = (unsigned short*)(embLast + (size_t)BB * GAT_TOT); // [288][64] bf16

    setup_kernel<<<1, 256, 0, stream>>>(coopW, confW, coopS, coopD, confS, confD, wt);

    gat_sage_kernel<<<BB * TT, 256, 0, stream>>>(
        selfF, nbF, mask, projW, projB, projG, projBt, wt,
        sageW, sageB, hsage, embLast);

    gru_head_kernel<<<BB, 256, 0, stream>>>(
        hsage, embLast,
        gfWx, gfWh, gfbx, gfbh, gbWx, gbWh, gbbx, gbbh,
        pW1, pb1, pg1, pbt1, pW2, pb2, pg2, pbt2, pWo, pbo,
        vW1, vb1, vg1, vbt1, vW2, vb2, vg2, vbt2, vWo, vbo,
        (float*)d_out);
}

// Round 8
// 1378.843 us; speedup vs baseline: 5.2986x; 5.2986x over previous
//
#include <hip/hip_runtime.h>
#include <math.h>

#define BB 4096
#define TT 5
#define KK 4
#define NLANES 12
#define GH 64
#define GO 32
#define GAT_TOT 256
#define SAGE_H 64
#define GRU_H 32

typedef __attribute__((ext_vector_type(8))) short short8v;
typedef __attribute__((ext_vector_type(8))) unsigned short ushort8v;
typedef __attribute__((ext_vector_type(4))) unsigned short ushort4v;
typedef __attribute__((ext_vector_type(4))) float f32x4;

__device__ __forceinline__ unsigned short f2bf(float x) {
    unsigned u = __float_as_uint(x);
    u += 0x7fffu + ((u >> 16) & 1u);
    return (unsigned short)(u >> 16);
}
__device__ __forceinline__ float bf2f(unsigned short b) {
    return __uint_as_float(((unsigned)b) << 16);
}

// ---------------------------------------------------------------------------
// Setup: W^T bf16 [256 cols][64 k] (round-4 version).
// ---------------------------------------------------------------------------
__global__ void wt_setup_kernel(const float* __restrict__ coopW,
                                const float* __restrict__ confW,
                                unsigned short* __restrict__ wt) {
    int c = threadIdx.x;                 // 256 threads, one col each
    int g = c >> 7, hh = (c >> 5) & 3, o = c & 31;
    const float* W = (g ? confW : coopW) + hh * (GH * GO) + o;
    for (int k = 0; k < GH; ++k)
        wt[c * GH + k] = f2bf(W[k * GO]);
}

// ---------------------------------------------------------------------------
// Kernel A: round-4 skeleton + (c) parallel array-free softmax +
// (d) float4 pool reads. NO second MFMA accumulator phase (differential test).
// ---------------------------------------------------------------------------
__global__ __launch_bounds__(256, 3) void gat_sage_kernel(
    const float* __restrict__ selfF, const float* __restrict__ nbF,
    const float* __restrict__ mask,
    const float* __restrict__ projW, const float* __restrict__ projB,
    const float* __restrict__ projG, const float* __restrict__ projBt,
    const float* __restrict__ coopSrc, const float* __restrict__ coopDst,
    const float* __restrict__ confSrc, const float* __restrict__ confDst,
    const unsigned short* __restrict__ wt,
    const float* __restrict__ sageW, const float* __restrict__ sageB,
    float* __restrict__ hsage, float* __restrict__ embLast)
{
    __shared__ __align__(16) float s_x[256];
    __shared__ __align__(16) unsigned short s_hb[64 * 64];   // 8 KB
    __shared__ __align__(16) char s_dyn[32768];              // WhT | s_att | in/part
    __shared__ float s_sd[2][8][60];

    unsigned short* WhT = (unsigned short*)s_dyn;                        // [256][64] bf16 swz
    float (*s_att)[8][NLANES][16] = (float (*)[8][NLANES][16])s_dyn;     // [5][8][12][16]
    float* s_in = (float*)s_dyn;                                         // [512]
    float (*s_part)[SAGE_H] = (float (*)[SAGE_H])(s_dyn + 2048);         // [4][64]

    const int bid = blockIdx.x;          // b*T + t
    const int b = bid / TT, t = bid % TT;
    const int tid = threadIdx.x;

    const int gh = tid >> 5, o = tid & 31;     // thread owns col = gh*32+o = tid
    const int wv = tid >> 6, f = tid & 63;     // wave, lane
    const int l15 = f & 15, g4 = f >> 4;

    // ---- stage inputs ----
    if (tid < 60) {
        int inst = tid / 12, j = tid % 12;
        const float* xp = (inst == 0)
            ? (selfF + (size_t)bid * 48)
            : (nbF + (size_t)((b * KK + (inst - 1)) * TT + t) * 48);
        ((float4*)s_x)[tid] = ((const float4*)xp)[j];
    }

    // proj row in registers (lane = feature f)
    const float pw0 = projW[0 * GH + f], pw1 = projW[1 * GH + f];
    const float pw2 = projW[2 * GH + f], pw3 = projW[3 * GH + f];
    const float pb = projB[f], pg = projG[f], pbt = projBt[f];
    __syncthreads();

    // ---- proj + LN + relu -> s_hb (bf16, frag-swizzled); rows 60..63 zero ----
    #pragma unroll
    for (int i = 0; i < 15; ++i) {
        const int r = wv + i * 4;
        float v = fmaf(s_x[r * 4 + 0], pw0, fmaf(s_x[r * 4 + 1], pw1,
                  fmaf(s_x[r * 4 + 2], pw2, fmaf(s_x[r * 4 + 3], pw3, pb))));
        float s1 = v, s2 = v * v;
        #pragma unroll
        for (int m = 1; m < 64; m <<= 1) {
            s1 += __shfl_xor(s1, m);
            s2 += __shfl_xor(s2, m);
        }
        float mean = s1 * (1.f / 64.f);
        float var  = s2 * (1.f / 64.f) - mean * mean;
        float nv = (v - mean) * rsqrtf(var + 1e-5f) * pg + pbt;
        nv = fmaxf(nv, 0.f);
        s_hb[r * 64 + (((f >> 3) ^ (r & 7)) << 3) + (f & 7)] = f2bf(nv);
    }
    {   // zero rows 60..63 (wave wv -> row 60+wv)
        const int r = 60 + wv;
        s_hb[r * 64 + (((f >> 3) ^ (r & 7)) << 3) + (f & 7)] = 0;
    }
    __syncthreads();

    // ---- GEMM: Wh = h[64x64] @ W[64x256], wave wv owns cols [64wv,64wv+64) ----
    {
        f32x4 c[4][4];
        #pragma unroll
        for (int mt = 0; mt < 4; ++mt)
            #pragma unroll
            for (int nt = 0; nt < 4; ++nt)
                c[mt][nt] = (f32x4){0.f, 0.f, 0.f, 0.f};

        #pragma unroll
        for (int kt = 0; kt < 2; ++kt) {
            const int kc = kt * 4 + g4;
            short8v a[4], bfr[4];
            #pragma unroll
            for (int mt = 0; mt < 4; ++mt) {
                const int r = mt * 16 + l15;
                a[mt] = *(const short8v*)&s_hb[r * 64 + ((kc ^ (r & 7)) << 3)];
            }
            #pragma unroll
            for (int nt = 0; nt < 4; ++nt)
                bfr[nt] = *(const short8v*)&wt[(wv * 64 + nt * 16 + l15) * GH + kc * 8];
            #pragma unroll
            for (int mt = 0; mt < 4; ++mt)
                #pragma unroll
                for (int nt = 0; nt < 4; ++nt)
                    c[mt][nt] = __builtin_amdgcn_mfma_f32_16x16x32_bf16(
                        a[mt], bfr[nt], c[mt][nt], 0, 0, 0);
        }

        // pack C frags -> WhT bf16 [col][64 rows], swizzled rows
        #pragma unroll
        for (int mt = 0; mt < 4; ++mt) {
            #pragma unroll
            for (int nt = 0; nt < 4; ++nt) {
                const int cc = wv * 64 + nt * 16 + l15;
                const int rb = mt * 16 + g4 * 4;           // 4 consecutive rows
                ushort4v p;
                p.x = f2bf(c[mt][nt][0]); p.y = f2bf(c[mt][nt][1]);
                p.z = f2bf(c[mt][nt][2]); p.w = f2bf(c[mt][nt][3]);
                const int idx = cc * 64 + (((rb >> 3) ^ (cc & 7)) << 3) + (rb & 7);
                *(ushort4v*)&WhT[idx] = p;
            }
        }
    }
    __syncthreads();

    // ---- readback: acc[r] = Wh[r][col=tid] ----
    float acc[60];
    {
        const int cs = tid & 7;
        #pragma unroll
        for (int ch = 0; ch < 8; ++ch) {
            ushort8v v = *(const ushort8v*)&WhT[tid * 64 + ((ch ^ cs) << 3)];
            #pragma unroll
            for (int j = 0; j < 8; ++j) {
                const int r = ch * 8 + j;
                if (r < 60) acc[r] = bf2f(v[j]);
            }
        }
    }
    __syncthreads();   // WhT dead; s_att region live from here

    // ---- attention src/dst scalars: shuffle-reduce, all 5 instances ----
    {
        const int g = gh >> 2, hh = gh & 3;
        const float as_v = (g ? confSrc : coopSrc)[hh * GO + o];
        const float ad_v = (g ? confDst : coopDst)[hh * GO + o];
        #pragma unroll
        for (int inst = 0; inst < 5; ++inst) {
            float sp[NLANES], dp[NLANES];
            #pragma unroll
            for (int n = 0; n < NLANES; ++n) {
                sp[n] = acc[inst * 12 + n] * as_v;
                dp[n] = acc[inst * 12 + n] * ad_v;
            }
            #pragma unroll
            for (int m = 1; m < 32; m <<= 1) {
                #pragma unroll
                for (int n = 0; n < NLANES; ++n) {
                    sp[n] += __shfl_xor(sp[n], m);
                    dp[n] += __shfl_xor(dp[n], m);
                }
            }
            if (o == 0) {
                #pragma unroll
                for (int n = 0; n < NLANES; ++n) {
                    s_sd[0][gh][inst * 12 + n] = sp[n];
                    s_sd[1][gh][inst * 12 + n] = dp[n];
                }
            }
        }
    }
    __syncthreads();

    // ---- parallel masked softmax: 480 tasks, array-free online ----
    #pragma unroll
    for (int round = 0; round < 2; ++round) {
        const int task = tid + round * 256;
        if (task < 480) {
            const int inst = task / 96;
            const int rem = task - inst * 96;
            const int gh2 = rem / 12, n2 = rem - (rem / 12) * 12;
            const int g2 = gh2 >> 2;
            const int an = n2 / 3;
            const float sn = s_sd[0][gh2][inst * 12 + n2];
            float mx = -1e30f, sum = 0.f;
            #pragma unroll
            for (int mm = 0; mm < NLANES; ++mm) {
                int am = mm / 3;
                bool valid = (g2 == 0) ? (am == an) : (am != an || mm == n2);
                if (valid) {
                    float ev = sn + s_sd[1][gh2][inst * 12 + mm];
                    ev = ev > 0.f ? ev : 0.2f * ev;
                    float nmx = fmaxf(mx, ev);
                    sum = sum * __expf(mx - nmx) + __expf(ev - nmx);
                    mx = nmx;
                }
            }
            const float inv = 1.f / sum;
            #pragma unroll
            for (int mm = 0; mm < NLANES; ++mm) {
                int am = mm / 3;
                bool valid = (g2 == 0) ? (am == an) : (am != an || mm == n2);
                float ev = sn + s_sd[1][gh2][inst * 12 + mm];
                ev = ev > 0.f ? ev : 0.2f * ev;
                s_att[inst][gh2][n2][mm] = valid ? __expf(ev - mx) * inv : 0.f;
            }
        }
    }
    __syncthreads();

    // ---- pool (float4 att reads) + agg + concat ----
    {
        float pooled_arr[5];
        #pragma unroll
        for (int inst = 0; inst < 5; ++inst) {
            float pooled = 0.f;
            #pragma unroll
            for (int n = 0; n < NLANES; ++n) {
                const float4* arow = (const float4*)s_att[inst][gh][n];
                float4 a0 = arow[0], a1 = arow[1], a2 = arow[2];
                float v = a0.x * acc[inst * 12 + 0] + a0.y * acc[inst * 12 + 1]
                        + a0.z * acc[inst * 12 + 2] + a0.w * acc[inst * 12 + 3]
                        + a1.x * acc[inst * 12 + 4] + a1.y * acc[inst * 12 + 5]
                        + a1.z * acc[inst * 12 + 6] + a1.w * acc[inst * 12 + 7]
                        + a2.x * acc[inst * 12 + 8] + a2.y * acc[inst * 12 + 9]
                        + a2.z * acc[inst * 12 + 10] + a2.w * acc[inst * 12 + 11];
                v = v > 0.f ? v : (__expf(v) - 1.f);
                pooled += v;
            }
            pooled_arr[inst] = pooled * (1.f / 12.f);
        }
        __syncthreads();   // att dead

        const float m0 = mask[b * KK + 0], m1 = mask[b * KK + 1];
        const float m2 = mask[b * KK + 2], m3 = mask[b * KK + 3];
        const float inv = 1.f / fmaxf(m0 + m1 + m2 + m3, 1.f);
        s_in[tid] = pooled_arr[0];
        s_in[GAT_TOT + tid] = (m0 * pooled_arr[1] + m1 * pooled_arr[2]
                             + m2 * pooled_arr[3] + m3 * pooled_arr[4]) * inv;
        if (t == TT - 1) embLast[(size_t)b * GAT_TOT + tid] = pooled_arr[0];
    }
    __syncthreads();

    // ---- central-node GraphSAGE row: split-K over 4 groups ----
    {
        const int j = tid & 63, q = tid >> 6;
        const float4* si4 = (const float4*)s_in;
        float v = 0.f;
        #pragma unroll 8
        for (int cq = q * 32; cq < q * 32 + 32; ++cq) {
            float4 s4 = si4[cq];
            const float* Wp = sageW + (cq * 4) * SAGE_H + j;
            v += s4.x * Wp[0] + s4.y * Wp[SAGE_H] + s4.z * Wp[2 * SAGE_H] + s4.w * Wp[3 * SAGE_H];
        }
        s_part[q][j] = v;
    }
    __syncthreads();
    if (tid < SAGE_H) {
        float v = sageB[tid] + s_part[0][tid] + s_part[1][tid]
                + s_part[2][tid] + s_part[3][tid];
        hsage[(size_t)bid * SAGE_H + tid] = fmaxf(v, 0.f);
    }
}

// ---------------------------------------------------------------------------
// Kernel B: per-b block, 256 threads (unchanged).
// ---------------------------------------------------------------------------
__global__ __launch_bounds__(256) void gru_head_kernel(
    const float* __restrict__ hsage, const float* __restrict__ embLast,
    const float* __restrict__ gfWx, const float* __restrict__ gfWh,
    const float* __restrict__ gfbx, const float* __restrict__ gfbh,
    const float* __restrict__ gbWx, const float* __restrict__ gbWh,
    const float* __restrict__ gbbx, const float* __restrict__ gbbh,
    const float* __restrict__ pW1, const float* __restrict__ pb1,
    const float* __restrict__ pg1, const float* __restrict__ pbt1,
    const float* __restrict__ pW2, const float* __restrict__ pb2,
    const float* __restrict__ pg2, const float* __restrict__ pbt2,
    const float* __restrict__ pWo, const float* __restrict__ pbo,
    const float* __restrict__ vW1, const float* __restrict__ vb1,
    const float* __restrict__ vg1, const float* __restrict__ vbt1,
    const float* __restrict__ vW2, const float* __restrict__ vb2,
    const float* __restrict__ vg2, const float* __restrict__ vbt2,
    const float* __restrict__ vWo, const float* __restrict__ vbo,
    float* __restrict__ dout)
{
    __shared__ float s_seq[TT * SAGE_H];
    __shared__ float s_gx[2][TT][96];
    __shared__ float s_hh[2][GRU_H];
    __shared__ float s_joint[320];
    __shared__ float s_h1[128];
    __shared__ float s_h2[64];
    __shared__ float s_p1[2][128];
    __shared__ float s_p2[4][64];
    __shared__ float s_red[4];

    const int b = blockIdx.x, tid = threadIdx.x;

    for (int i = tid; i < TT * SAGE_H; i += 256) s_seq[i] = hsage[(size_t)b * TT * SAGE_H + i];
    s_joint[tid] = embLast[(size_t)b * GAT_TOT + tid];
    if (tid < 64) s_hh[tid >> 5][tid & 31] = 0.f;
    __syncthreads();

    for (int task = tid; task < 960; task += 256) {
        int dir = task >= 480;
        int rem = task - dir * 480;
        int t5 = rem / 96, j = rem - t5 * 96;
        const float* Wx = dir ? gbWx : gfWx;
        const float* bx = dir ? gbbx : gfbx;
        const float* x = &s_seq[t5 * SAGE_H];
        float v = bx[j];
        for (int f2 = 0; f2 < SAGE_H; ++f2) v += x[f2] * Wx[f2 * 96 + j];
        s_gx[dir][t5][j] = v;
    }
    __syncthreads();

    for (int s = 0; s < TT; ++s) {
        float hnew = 0.f;
        if (tid < 64) {
            int dir = tid >> 5, j = tid & 31;
            int t5 = dir ? (TT - 1 - s) : s;
            const float* Wh = dir ? gbWh : gfWh;
            const float* bh = dir ? gbbh : gfbh;
            const float* h = s_hh[dir];
            float hr = bh[j], hz = bh[32 + j], hn = bh[64 + j];
            for (int k = 0; k < GRU_H; ++k) {
                float hv = h[k];
                hr += hv * Wh[k * 96 + j];
                hz += hv * Wh[k * 96 + 32 + j];
                hn += hv * Wh[k * 96 + 64 + j];
            }
            float xr = s_gx[dir][t5][j], xz = s_gx[dir][t5][32 + j], xn = s_gx[dir][t5][64 + j];
            float r = 1.f / (1.f + __expf(-(xr + hr)));
            float z = 1.f / (1.f + __expf(-(xz + hz)));
            float nn = tanhf(xn + r * hn);
            hnew = (1.f - z) * nn + z * h[j];
        }
        __syncthreads();
        if (tid < 64) s_hh[tid >> 5][tid & 31] = hnew;
        __syncthreads();
    }
    if (tid < 64) s_joint[GAT_TOT + tid] = s_hh[tid >> 5][tid & 31];
    __syncthreads();

    for (int hd = 0; hd < 2; ++hd) {
        const float* W1 = hd ? vW1 : pW1;  const float* b1 = hd ? vb1 : pb1;
        const float* g1 = hd ? vg1 : pg1;  const float* bt1 = hd ? vbt1 : pbt1;
        const float* W2 = hd ? vW2 : pW2;  const float* b2 = hd ? vb2 : pb2;
        const float* g2 = hd ? vg2 : pg2;  const float* bt2 = hd ? vbt2 : pbt2;
        const float* Wo = hd ? vWo : pWo;  const float* bo = hd ? vbo : pbo;

        {
            int j = tid & 127, hf = tid >> 7;
            float v = (hf == 0) ? b1[j] : 0.f;
            for (int c2 = hf * 160; c2 < hf * 160 + 160; ++c2)
                v += s_joint[c2] * W1[c2 * 128 + j];
            s_p1[hf][j] = v;
        }
        __syncthreads();
        if (tid < 128) {
            float vv = s_p1[0][tid] + s_p1[1][tid];
            float q1 = vv, q2 = vv * vv;
            #pragma unroll
            for (int m = 1; m < 64; m <<= 1) { q1 += __shfl_xor(q1, m); q2 += __shfl_xor(q2, m); }
            if ((tid & 63) == 0) { s_red[(tid >> 6) * 2] = q1; s_red[(tid >> 6) * 2 + 1] = q2; }
        }
        __syncthreads();
        if (tid < 128) {
            float sum1 = s_red[0] + s_red[2], sum2 = s_red[1] + s_red[3];
            float mean = sum1 * (1.f / 128.f);
            float var = sum2 * (1.f / 128.f) - mean * mean;
            float vv = s_p1[0][tid] + s_p1[1][tid];
            s_h1[tid] = fmaxf((vv - mean) * rsqrtf(var + 1e-5f) * g1[tid] + bt1[tid], 0.f);
        }
        __syncthreads();

        {
            int j = tid & 63, q = tid >> 6;
            float v = (q == 0) ? b2[j] : 0.f;
            for (int c2 = q * 32; c2 < q * 32 + 32; ++c2)
                v += s_h1[c2] * W2[c2 * 64 + j];
            s_p2[q][j] = v;
        }
        __syncthreads();
        if (tid < 64) {
            float vv = s_p2[0][tid] + s_p2[1][tid] + s_p2[2][tid] + s_p2[3][tid];
            float q1 = vv, q2 = vv * vv;
            #pragma unroll
            for (int m = 1; m < 64; m <<= 1) { q1 += __shfl_xor(q1, m); q2 += __shfl_xor(q2, m); }
            float mean = q1 * (1.f / 64.f);
            float var = q2 * (1.f / 64.f) - mean * mean;
            s_h2[tid] = fmaxf((vv - mean) * rsqrtf(var + 1e-5f) * g2[tid] + bt2[tid], 0.f);
        }
        __syncthreads();

        if (hd == 0) {
            if (tid < 8) {
                float v3 = bo[tid];
                for (int c2 = 0; c2 < 64; ++c2) v3 += s_h2[c2] * Wo[c2 * 8 + tid];
                dout[(size_t)b * 8 + tid] = v3;
            }
        } else {
            if (tid == 0) {
                float v3 = bo[0];
                for (int c2 = 0; c2 < 64; ++c2) v3 += s_h2[c2] * Wo[c2];
                dout[(size_t)BB * 8 + b] = v3;
            }
        }
        __syncthreads();
    }
}

extern "C" void kernel_launch(void* const* d_in, const int* in_sizes, int n_in,
                              void* d_out, int out_size, void* d_ws, size_t ws_size,
                              hipStream_t stream) {
    (void)in_sizes; (void)n_in; (void)out_size; (void)ws_size;
    const float* selfF  = (const float*)d_in[0];
    const float* nbF    = (const float*)d_in[1];
    const float* mask   = (const float*)d_in[2];
    const float* projW  = (const float*)d_in[3];
    const float* projB  = (const float*)d_in[4];
    const float* projG  = (const float*)d_in[5];
    const float* projBt = (const float*)d_in[6];
    const float* coopW  = (const float*)d_in[7];
    const float* coopS  = (const float*)d_in[8];
    const float* coopD  = (const float*)d_in[9];
    const float* confW  = (const float*)d_in[10];
    const float* confS  = (const float*)d_in[11];
    const float* confD  = (const float*)d_in[12];
    const float* sageW  = (const float*)d_in[13];
    const float* sageB  = (const float*)d_in[14];
    const float* gfWx = (const float*)d_in[15];
    const float* gfWh = (const float*)d_in[16];
    const float* gfbx = (const float*)d_in[17];
    const float* gfbh = (const float*)d_in[18];
    const float* gbWx = (const float*)d_in[19];
    const float* gbWh = (const float*)d_in[20];
    const float* gbbx = (const float*)d_in[21];
    const float* gbbh = (const float*)d_in[22];
    const float* pW1  = (const float*)d_in[23];
    const float* pb1  = (const float*)d_in[24];
    const float* pg1  = (const float*)d_in[25];
    const float* pbt1 = (const float*)d_in[26];
    const float* pW2  = (const float*)d_in[27];
    const float* pb2  = (const float*)d_in[28];
    const float* pg2  = (const float*)d_in[29];
    const float* pbt2 = (const float*)d_in[30];
    const float* pWo  = (const float*)d_in[31];
    const float* pbo  = (const float*)d_in[32];
    const float* vW1  = (const float*)d_in[33];
    const float* vb1  = (const float*)d_in[34];
    const float* vg1  = (const float*)d_in[35];
    const float* vbt1 = (const float*)d_in[36];
    const float* vW2  = (const float*)d_in[37];
    const float* vb2  = (const float*)d_in[38];
    const float* vg2  = (const float*)d_in[39];
    const float* vbt2 = (const float*)d_in[40];
    const float* vWo  = (const float*)d_in[41];
    const float* vbo  = (const float*)d_in[42];

    float* hsage   = (float*)d_ws;                                    // B*T*64 f32
    float* embLast = hsage + (size_t)BB * TT * SAGE_H;                // B*256 f32
    unsigned short* wt = (unsigned short*)(embLast + (size_t)BB * GAT_TOT); // [256][64] bf16

    wt_setup_kernel<<<1, 256, 0, stream>>>(coopW, confW, wt);

    gat_sage_kernel<<<BB * TT, 256, 0, stream>>>(
        selfF, nbF, mask, projW, projB, projG, projBt,
        coopS, coopD, confS, confD, wt,
        sageW, sageB, hsage, embLast);

    gru_head_kernel<<<BB, 256, 0, stream>>>(
        hsage, embLast,
        gfWx, gfWh, gfbx, gfbh, gbWx, gbWh, gbbx, gbbh,
        pW1, pb1, pg1, pbt1, pW2, pb2, pg2, pbt2, pWo, pbo,
        vW1, vb1, vg1, vbt1, vW2, vb2, vg2, vbt2, vWo, vbo,
        (float*)d_out);
}

// Round 9
// 935.614 us; speedup vs baseline: 7.8087x; 1.4737x over previous
//
#include <hip/hip_runtime.h>
#include <hip/hip_bf16.h>
#include <math.h>

#define BB 4096
#define TT 5
#define KK 4
#define NLANES 12
#define GH 64
#define GO 32
#define GAT_TOT 256
#define SAGE_H 64
#define GRU_H 32

typedef __attribute__((ext_vector_type(8))) short short8v;
typedef __attribute__((ext_vector_type(8))) unsigned short ushort8v;
typedef __attribute__((ext_vector_type(4))) unsigned short ushort4v;
typedef __attribute__((ext_vector_type(4))) float f32x4;

__device__ __forceinline__ unsigned short f2bf(float x) {
    __hip_bfloat16 h = __float2bfloat16(x);
    return __builtin_bit_cast(unsigned short, h);
}
__device__ __forceinline__ float bf2f(unsigned short b) {
    return __uint_as_float(((unsigned)b) << 16);
}

// ---------------------------------------------------------------------------
// Setup: wt bf16 [256][64] (W^T) + statc[20] LN quadratic-form coefficients:
//  [0..9]  S'cd (c<=d, off-diag pre-doubled)  [10..13] 2*Cb  [14] Vb
//  [15..18] Wm  [19] bm
// ---------------------------------------------------------------------------
__global__ void setup_kernel(const float* __restrict__ coopW,
                             const float* __restrict__ confW,
                             const float* __restrict__ projW,
                             const float* __restrict__ projB,
                             unsigned short* __restrict__ wt,
                             float* __restrict__ statc) {
    const int tnum = threadIdx.x;   // 256 threads
    {
        int c = tnum;
        int g = c >> 7, hh = (c >> 5) & 3, o = c & 31;
        const float* W = (g ? confW : coopW) + hh * (GH * GO) + o;
        for (int k = 0; k < GH; ++k)
            wt[c * GH + k] = f2bf(W[k * GO]);
    }
    if (tnum == 0) {
        float Wm[4], bm = 0.f;
        for (int c = 0; c < 4; ++c) {
            float s = 0.f;
            for (int f = 0; f < GH; ++f) s += projW[c * GH + f];
            Wm[c] = s * (1.f / GH);
        }
        for (int f = 0; f < GH; ++f) bm += projB[f];
        bm *= (1.f / GH);
        int idx = 0;
        for (int c = 0; c < 4; ++c)
            for (int d = c; d < 4; ++d) {
                float s = 0.f;
                for (int f = 0; f < GH; ++f)
                    s += (projW[c * GH + f] - Wm[c]) * (projW[d * GH + f] - Wm[d]);
                statc[idx++] = s * (1.f / GH) * (c == d ? 1.f : 2.f);
            }
        for (int c = 0; c < 4; ++c) {
            float s = 0.f;
            for (int f = 0; f < GH; ++f)
                s += (projW[c * GH + f] - Wm[c]) * (projB[f] - bm);
            statc[10 + c] = s * (2.f / GH);
        }
        {
            float s = 0.f;
            for (int f = 0; f < GH; ++f)
                s += (projB[f] - bm) * (projB[f] - bm);
            statc[14] = s * (1.f / GH);
        }
        for (int c = 0; c < 4; ++c) statc[15 + c] = Wm[c];
        statc[19] = bm;
    }
}

// ---------------------------------------------------------------------------
// Kernel A: r8 skeleton + (1) attention-scalar reduce folded into C-pack,
// (2) covariance-LN (shuffle-free), (3) XOR-swizzled s_att quads.
// ---------------------------------------------------------------------------
__global__ __launch_bounds__(256, 3) void gat_sage_kernel(
    const float* __restrict__ selfF, const float* __restrict__ nbF,
    const float* __restrict__ mask,
    const float* __restrict__ projW, const float* __restrict__ projB,
    const float* __restrict__ projG, const float* __restrict__ projBt,
    const float* __restrict__ coopSrc, const float* __restrict__ coopDst,
    const float* __restrict__ confSrc, const float* __restrict__ confDst,
    const unsigned short* __restrict__ wt, const float* __restrict__ statc,
    const float* __restrict__ sageW, const float* __restrict__ sageB,
    float* __restrict__ hsage, float* __restrict__ embLast)
{
    __shared__ __align__(16) float s_x[256];
    __shared__ __align__(16) float2 s_stat[64];
    __shared__ __align__(16) unsigned short s_hb[64 * 64];   // 8 KB
    __shared__ __align__(16) char s_dyn[32768];              // WhT | s_att | in/part
    __shared__ __align__(16) float s_sd[2][8][64];           // 4 KB

    unsigned short* WhT = (unsigned short*)s_dyn;                        // [256][64] bf16 swz
    float (*s_att)[8][NLANES][16] = (float (*)[8][NLANES][16])s_dyn;     // [5][8][12][16]
    float* s_in = (float*)s_dyn;                                         // [512]
    float (*s_part)[SAGE_H] = (float (*)[SAGE_H])(s_dyn + 2048);         // [4][64]

    const int bid = blockIdx.x;          // b*T + t
    const int b = bid / TT, t = bid % TT;
    const int tid = threadIdx.x;

    const int gh = tid >> 5;                   // pool: col = tid
    const int wv = tid >> 6, f = tid & 63;     // wave, lane
    const int l15 = f & 15, g4 = f >> 4;

    // ---- stage inputs + per-row LN stats (covariance trick, same thread) ----
    if (tid < 60) {
        int inst = tid / 12, j = tid % 12;
        const float* xp = (inst == 0)
            ? (selfF + (size_t)bid * 48)
            : (nbF + (size_t)((b * KK + (inst - 1)) * TT + t) * 48);
        float4 xv = ((const float4*)xp)[j];
        ((float4*)s_x)[tid] = xv;
        const float* sc = statc;
        float mean = xv.x * sc[15] + xv.y * sc[16] + xv.z * sc[17] + xv.w * sc[18] + sc[19];
        float var = sc[0] * xv.x * xv.x + sc[1] * xv.x * xv.y + sc[2] * xv.x * xv.z
                  + sc[3] * xv.x * xv.w + sc[4] * xv.y * xv.y + sc[5] * xv.y * xv.z
                  + sc[6] * xv.y * xv.w + sc[7] * xv.z * xv.z + sc[8] * xv.z * xv.w
                  + sc[9] * xv.w * xv.w
                  + sc[10] * xv.x + sc[11] * xv.y + sc[12] * xv.z + sc[13] * xv.w + sc[14];
        s_stat[tid] = make_float2(mean, rsqrtf(fmaxf(var, 0.f) + 1e-5f));
    }

    // proj row in registers (lane = feature f)
    const float pw0 = projW[0 * GH + f], pw1 = projW[1 * GH + f];
    const float pw2 = projW[2 * GH + f], pw3 = projW[3 * GH + f];
    const float pb = projB[f], pg = projG[f], pbt = projBt[f];
    __syncthreads();

    // ---- proj + LN + relu -> s_hb (bf16, frag-swizzled); rows 60..63 zero ----
    #pragma unroll
    for (int i = 0; i < 15; ++i) {
        const int r = wv + i * 4;
        float2 st = s_stat[r];
        float h = fmaf(s_x[r * 4 + 0], pw0, fmaf(s_x[r * 4 + 1], pw1,
                  fmaf(s_x[r * 4 + 2], pw2, fmaf(s_x[r * 4 + 3], pw3, pb))));
        float nv = (h - st.x) * (st.y * pg) + pbt;
        nv = fmaxf(nv, 0.f);
        s_hb[r * 64 + (((f >> 3) ^ (r & 7)) << 3) + (f & 7)] = f2bf(nv);
    }
    {   // zero rows 60..63 (wave wv -> row 60+wv)
        const int r = 60 + wv;
        s_hb[r * 64 + (((f >> 3) ^ (r & 7)) << 3) + (f & 7)] = 0;
    }
    __syncthreads();

    // ---- GEMM: Wh = h[64x64] @ W[64x256]; reduce + pack from C-frags ----
    {
        f32x4 c[4][4];
        #pragma unroll
        for (int mt = 0; mt < 4; ++mt)
            #pragma unroll
            for (int nt = 0; nt < 4; ++nt)
                c[mt][nt] = (f32x4){0.f, 0.f, 0.f, 0.f};

        #pragma unroll
        for (int kt = 0; kt < 2; ++kt) {
            const int kc = kt * 4 + g4;
            short8v a[4], bfr[4];
            #pragma unroll
            for (int mt = 0; mt < 4; ++mt) {
                const int r = mt * 16 + l15;
                a[mt] = *(const short8v*)&s_hb[r * 64 + ((kc ^ (r & 7)) << 3)];
            }
            #pragma unroll
            for (int nt = 0; nt < 4; ++nt)
                bfr[nt] = *(const short8v*)&wt[(wv * 64 + nt * 16 + l15) * GH + kc * 8];
            #pragma unroll
            for (int mt = 0; mt < 4; ++mt)
                #pragma unroll
                for (int nt = 0; nt < 4; ++nt)
                    c[mt][nt] = __builtin_amdgcn_mfma_f32_16x16x32_bf16(
                        a[mt], bfr[nt], c[mt][nt], 0, 0, 0);
        }

        // attention scalars from C-frags: 16-lane shuffle reduce over l15
        {
            float asv[4], adv[4];
            #pragma unroll
            for (int nt = 0; nt < 4; ++nt) {
                const int cc = wv * 64 + nt * 16 + l15;
                const int g = cc >> 7, hh = (cc >> 5) & 3, oo = cc & 31;
                asv[nt] = (g ? confSrc : coopSrc)[hh * GO + oo];
                adv[nt] = (g ? confDst : coopDst)[hh * GO + oo];
            }
            #pragma unroll
            for (int p = 0; p < 2; ++p) {
                const int ghw = 2 * wv + p;
                #pragma unroll
                for (int mt = 0; mt < 4; ++mt) {
                    float sv[4], dv[4];
                    #pragma unroll
                    for (int r = 0; r < 4; ++r) {
                        sv[r] = c[mt][2 * p][r] * asv[2 * p] + c[mt][2 * p + 1][r] * asv[2 * p + 1];
                        dv[r] = c[mt][2 * p][r] * adv[2 * p] + c[mt][2 * p + 1][r] * adv[2 * p + 1];
                    }
                    #pragma unroll
                    for (int m = 1; m < 16; m <<= 1) {
                        #pragma unroll
                        for (int r = 0; r < 4; ++r) {
                            sv[r] += __shfl_xor(sv[r], m);
                            dv[r] += __shfl_xor(dv[r], m);
                        }
                    }
                    if (l15 == 0) {
                        const int rb = mt * 16 + g4 * 4;
                        *(float4*)&s_sd[0][ghw][rb] = make_float4(sv[0], sv[1], sv[2], sv[3]);
                        *(float4*)&s_sd[1][ghw][rb] = make_float4(dv[0], dv[1], dv[2], dv[3]);
                    }
                }
            }
        }

        // pack C frags -> WhT bf16 [col][64 rows], swizzled rows
        #pragma unroll
        for (int mt = 0; mt < 4; ++mt) {
            #pragma unroll
            for (int nt = 0; nt < 4; ++nt) {
                const int cc = wv * 64 + nt * 16 + l15;
                const int rb = mt * 16 + g4 * 4;
                ushort4v p;
                p.x = f2bf(c[mt][nt][0]); p.y = f2bf(c[mt][nt][1]);
                p.z = f2bf(c[mt][nt][2]); p.w = f2bf(c[mt][nt][3]);
                const int idx = cc * 64 + (((rb >> 3) ^ (cc & 7)) << 3) + (rb & 7);
                *(ushort4v*)&WhT[idx] = p;
            }
        }
    }
    __syncthreads();

    // ---- readback: acc[r] = Wh[r][col=tid] ----
    float acc[60];
    {
        const int cs = tid & 7;
        #pragma unroll
        for (int ch = 0; ch < 8; ++ch) {
            ushort8v v = *(const ushort8v*)&WhT[tid * 64 + ((ch ^ cs) << 3)];
            #pragma unroll
            for (int j = 0; j < 8; ++j) {
                const int r = ch * 8 + j;
                if (r < 60) acc[r] = bf2f(v[j]);
            }
        }
    }
    __syncthreads();   // WhT dead; s_att region live from here

    // ---- parallel masked softmax: 480 tasks, array-free, swizzled writes ----
    #pragma unroll
    for (int round = 0; round < 2; ++round) {
        const int task = tid + round * 256;
        if (task < 480) {
            const int inst = task / 96;
            const int rem = task - inst * 96;
            const int gh2 = rem / 12, n2 = rem - (rem / 12) * 12;
            const int g2 = gh2 >> 2;
            const int an = n2 / 3;
            const float sn = s_sd[0][gh2][inst * 12 + n2];
            float mx = -1e30f, sum = 0.f;
            #pragma unroll
            for (int mm = 0; mm < NLANES; ++mm) {
                int am = mm / 3;
                bool valid = (g2 == 0) ? (am == an) : (am != an || mm == n2);
                if (valid) {
                    float ev = sn + s_sd[1][gh2][inst * 12 + mm];
                    ev = ev > 0.f ? ev : 0.2f * ev;
                    float nmx = fmaxf(mx, ev);
                    sum = sum * __expf(mx - nmx) + __expf(ev - nmx);
                    mx = nmx;
                }
            }
            const float inv = 1.f / sum;
            float vq[12];
            #pragma unroll
            for (int mm = 0; mm < NLANES; ++mm) {
                int am = mm / 3;
                bool valid = (g2 == 0) ? (am == an) : (am != an || mm == n2);
                float ev = sn + s_sd[1][gh2][inst * 12 + mm];
                ev = ev > 0.f ? ev : 0.2f * ev;
                vq[mm] = valid ? __expf(ev - mx) * inv : 0.f;
            }
            const int sw = n2 & 3;
            float4* arow = (float4*)s_att[inst][gh2][n2];
            arow[0 ^ sw] = make_float4(vq[0], vq[1], vq[2], vq[3]);
            arow[1 ^ sw] = make_float4(vq[4], vq[5], vq[6], vq[7]);
            arow[2 ^ sw] = make_float4(vq[8], vq[9], vq[10], vq[11]);
        }
    }
    __syncthreads();

    // ---- pool (swizzled float4 att reads) + agg + concat ----
    {
        float pooled_arr[5];
        #pragma unroll
        for (int inst = 0; inst < 5; ++inst) {
            float pooled = 0.f;
            #pragma unroll
            for (int n = 0; n < NLANES; ++n) {
                const int sw = n & 3;
                const float4* arow = (const float4*)s_att[inst][gh][n];
                float4 a0 = arow[0 ^ sw], a1 = arow[1 ^ sw], a2 = arow[2 ^ sw];
                float v = a0.x * acc[inst * 12 + 0] + a0.y * acc[inst * 12 + 1]
                        + a0.z * acc[inst * 12 + 2] + a0.w * acc[inst * 12 + 3]
                        + a1.x * acc[inst * 12 + 4] + a1.y * acc[inst * 12 + 5]
                        + a1.z * acc[inst * 12 + 6] + a1.w * acc[inst * 12 + 7]
                        + a2.x * acc[inst * 12 + 8] + a2.y * acc[inst * 12 + 9]
                        + a2.z * acc[inst * 12 + 10] + a2.w * acc[inst * 12 + 11];
                v = v > 0.f ? v : (__expf(v) - 1.f);
                pooled += v;
            }
            pooled_arr[inst] = pooled * (1.f / 12.f);
        }
        __syncthreads();   // att dead

        const float m0 = mask[b * KK + 0], m1 = mask[b * KK + 1];
        const float m2 = mask[b * KK + 2], m3 = mask[b * KK + 3];
        const float inv = 1.f / fmaxf(m0 + m1 + m2 + m3, 1.f);
        s_in[tid] = pooled_arr[0];
        s_in[GAT_TOT + tid] = (m0 * pooled_arr[1] + m1 * pooled_arr[2]
                             + m2 * pooled_arr[3] + m3 * pooled_arr[4]) * inv;
        if (t == TT - 1) embLast[(size_t)b * GAT_TOT + tid] = pooled_arr[0];
    }
    __syncthreads();

    // ---- central-node GraphSAGE row: split-K over 4 groups ----
    {
        const int j = tid & 63, q = tid >> 6;
        const float4* si4 = (const float4*)s_in;
        float v = 0.f;
        #pragma unroll 8
        for (int cq = q * 32; cq < q * 32 + 32; ++cq) {
            float4 s4 = si4[cq];
            const float* Wp = sageW + (cq * 4) * SAGE_H + j;
            v += s4.x * Wp[0] + s4.y * Wp[SAGE_H] + s4.z * Wp[2 * SAGE_H] + s4.w * Wp[3 * SAGE_H];
        }
        s_part[q][j] = v;
    }
    __syncthreads();
    if (tid < SAGE_H) {
        float v = sageB[tid] + s_part[0][tid] + s_part[1][tid]
                + s_part[2][tid] + s_part[3][tid];
        hsage[(size_t)bid * SAGE_H + tid] = fmaxf(v, 0.f);
    }
}

// ---------------------------------------------------------------------------
// Kernel B: per-b block, 256 threads (unchanged).
// ---------------------------------------------------------------------------
__global__ __launch_bounds__(256) void gru_head_kernel(
    const float* __restrict__ hsage, const float* __restrict__ embLast,
    const float* __restrict__ gfWx, const float* __restrict__ gfWh,
    const float* __restrict__ gfbx, const float* __restrict__ gfbh,
    const float* __restrict__ gbWx, const float* __restrict__ gbWh,
    const float* __restrict__ gbbx, const float* __restrict__ gbbh,
    const float* __restrict__ pW1, const float* __restrict__ pb1,
    const float* __restrict__ pg1, const float* __restrict__ pbt1,
    const float* __restrict__ pW2, const float* __restrict__ pb2,
    const float* __restrict__ pg2, const float* __restrict__ pbt2,
    const float* __restrict__ pWo, const float* __restrict__ pbo,
    const float* __restrict__ vW1, const float* __restrict__ vb1,
    const float* __restrict__ vg1, const float* __restrict__ vbt1,
    const float* __restrict__ vW2, const float* __restrict__ vb2,
    const float* __restrict__ vg2, const float* __restrict__ vbt2,
    const float* __restrict__ vWo, const float* __restrict__ vbo,
    float* __restrict__ dout)
{
    __shared__ float s_seq[TT * SAGE_H];
    __shared__ float s_gx[2][TT][96];
    __shared__ float s_hh[2][GRU_H];
    __shared__ float s_joint[320];
    __shared__ float s_h1[128];
    __shared__ float s_h2[64];
    __shared__ float s_p1[2][128];
    __shared__ float s_p2[4][64];
    __shared__ float s_red[4];

    const int b = blockIdx.x, tid = threadIdx.x;

    for (int i = tid; i < TT * SAGE_H; i += 256) s_seq[i] = hsage[(size_t)b * TT * SAGE_H + i];
    s_joint[tid] = embLast[(size_t)b * GAT_TOT + tid];
    if (tid < 64) s_hh[tid >> 5][tid & 31] = 0.f;
    __syncthreads();

    for (int task = tid; task < 960; task += 256) {
        int dir = task >= 480;
        int rem = task - dir * 480;
        int t5 = rem / 96, j = rem - t5 * 96;
        const float* Wx = dir ? gbWx : gfWx;
        const float* bx = dir ? gbbx : gfbx;
        const float* x = &s_seq[t5 * SAGE_H];
        float v = bx[j];
        for (int f2 = 0; f2 < SAGE_H; ++f2) v += x[f2] * Wx[f2 * 96 + j];
        s_gx[dir][t5][j] = v;
    }
    __syncthreads();

    for (int s = 0; s < TT; ++s) {
        float hnew = 0.f;
        if (tid < 64) {
            int dir = tid >> 5, j = tid & 31;
            int t5 = dir ? (TT - 1 - s) : s;
            const float* Wh = dir ? gbWh : gfWh;
            const float* bh = dir ? gbbh : gfbh;
            const float* h = s_hh[dir];
            float hr = bh[j], hz = bh[32 + j], hn = bh[64 + j];
            for (int k = 0; k < GRU_H; ++k) {
                float hv = h[k];
                hr += hv * Wh[k * 96 + j];
                hz += hv * Wh[k * 96 + 32 + j];
                hn += hv * Wh[k * 96 + 64 + j];
            }
            float xr = s_gx[dir][t5][j], xz = s_gx[dir][t5][32 + j], xn = s_gx[dir][t5][64 + j];
            float r = 1.f / (1.f + __expf(-(xr + hr)));
            float z = 1.f / (1.f + __expf(-(xz + hz)));
            float nn = tanhf(xn + r * hn);
            hnew = (1.f - z) * nn + z * h[j];
        }
        __syncthreads();
        if (tid < 64) s_hh[tid >> 5][tid & 31] = hnew;
        __syncthreads();
    }
    if (tid < 64) s_joint[GAT_TOT + tid] = s_hh[tid >> 5][tid & 31];
    __syncthreads();

    for (int hd = 0; hd < 2; ++hd) {
        const float* W1 = hd ? vW1 : pW1;  const float* b1 = hd ? vb1 : pb1;
        const float* g1 = hd ? vg1 : pg1;  const float* bt1 = hd ? vbt1 : pbt1;
        const float* W2 = hd ? vW2 : pW2;  const float* b2 = hd ? vb2 : pb2;
        const float* g2 = hd ? vg2 : pg2;  const float* bt2 = hd ? vbt2 : pbt2;
        const float* Wo = hd ? vWo : pWo;  const float* bo = hd ? vbo : pbo;

        {
            int j = tid & 127, hf = tid >> 7;
            float v = (hf == 0) ? b1[j] : 0.f;
            for (int c2 = hf * 160; c2 < hf * 160 + 160; ++c2)
                v += s_joint[c2] * W1[c2 * 128 + j];
            s_p1[hf][j] = v;
        }
        __syncthreads();
        if (tid < 128) {
            float vv = s_p1[0][tid] + s_p1[1][tid];
            float q1 = vv, q2 = vv * vv;
            #pragma unroll
            for (int m = 1; m < 64; m <<= 1) { q1 += __shfl_xor(q1, m); q2 += __shfl_xor(q2, m); }
            if ((tid & 63) == 0) { s_red[(tid >> 6) * 2] = q1; s_red[(tid >> 6) * 2 + 1] = q2; }
        }
        __syncthreads();
        if (tid < 128) {
            float sum1 = s_red[0] + s_red[2], sum2 = s_red[1] + s_red[3];
            float mean = sum1 * (1.f / 128.f);
            float var = sum2 * (1.f / 128.f) - mean * mean;
            float vv = s_p1[0][tid] + s_p1[1][tid];
            s_h1[tid] = fmaxf((vv - mean) * rsqrtf(var + 1e-5f) * g1[tid] + bt1[tid], 0.f);
        }
        __syncthreads();

        {
            int j = tid & 63, q = tid >> 6;
            float v = (q == 0) ? b2[j] : 0.f;
            for (int c2 = q * 32; c2 < q * 32 + 32; ++c2)
                v += s_h1[c2] * W2[c2 * 64 + j];
            s_p2[q][j] = v;
        }
        __syncthreads();
        if (tid < 64) {
            float vv = s_p2[0][tid] + s_p2[1][tid] + s_p2[2][tid] + s_p2[3][tid];
            float q1 = vv, q2 = vv * vv;
            #pragma unroll
            for (int m = 1; m < 64; m <<= 1) { q1 += __shfl_xor(q1, m); q2 += __shfl_xor(q2, m); }
            float mean = q1 * (1.f / 64.f);
            float var = q2 * (1.f / 64.f) - mean * mean;
            s_h2[tid] = fmaxf((vv - mean) * rsqrtf(var + 1e-5f) * g2[tid] + bt2[tid], 0.f);
        }
        __syncthreads();

        if (hd == 0) {
            if (tid < 8) {
                float v3 = bo[tid];
                for (int c2 = 0; c2 < 64; ++c2) v3 += s_h2[c2] * Wo[c2 * 8 + tid];
                dout[(size_t)b * 8 + tid] = v3;
            }
        } else {
            if (tid == 0) {
                float v3 = bo[0];
                for (int c2 = 0; c2 < 64; ++c2) v3 += s_h2[c2] * Wo[c2];
                dout[(size_t)BB * 8 + b] = v3;
            }
        }
        __syncthreads();
    }
}

extern "C" void kernel_launch(void* const* d_in, const int* in_sizes, int n_in,
                              void* d_out, int out_size, void* d_ws, size_t ws_size,
                              hipStream_t stream) {
    (void)in_sizes; (void)n_in; (void)out_size; (void)ws_size;
    const float* selfF  = (const float*)d_in[0];
    const float* nbF    = (const float*)d_in[1];
    const float* mask   = (const float*)d_in[2];
    const float* projW  = (const float*)d_in[3];
    const float* projB  = (const float*)d_in[4];
    const float* projG  = (const float*)d_in[5];
    const float* projBt = (const float*)d_in[6];
    const float* coopW  = (const float*)d_in[7];
    const float* coopS  = (const float*)d_in[8];
    const float* coopD  = (const float*)d_in[9];
    const float* confW  = (const float*)d_in[10];
    const float* confS  = (const float*)d_in[11];
    const float* confD  = (const float*)d_in[12];
    const float* sageW  = (const float*)d_in[13];
    const float* sageB  = (const float*)d_in[14];
    const float* gfWx = (const float*)d_in[15];
    const float* gfWh = (const float*)d_in[16];
    const float* gfbx = (const float*)d_in[17];
    const float* gfbh = (const float*)d_in[18];
    const float* gbWx = (const float*)d_in[19];
    const float* gbWh = (const float*)d_in[20];
    const float* gbbx = (const float*)d_in[21];
    const float* gbbh = (const float*)d_in[22];
    const float* pW1  = (const float*)d_in[23];
    const float* pb1  = (const float*)d_in[24];
    const float* pg1  = (const float*)d_in[25];
    const float* pbt1 = (const float*)d_in[26];
    const float* pW2  = (const float*)d_in[27];
    const float* pb2  = (const float*)d_in[28];
    const float* pg2  = (const float*)d_in[29];
    const float* pbt2 = (const float*)d_in[30];
    const float* pWo  = (const float*)d_in[31];
    const float* pbo  = (const float*)d_in[32];
    const float* vW1  = (const float*)d_in[33];
    const float* vb1  = (const float*)d_in[34];
    const float* vg1  = (const float*)d_in[35];
    const float* vbt1 = (const float*)d_in[36];
    const float* vW2  = (const float*)d_in[37];
    const float* vb2  = (const float*)d_in[38];
    const float* vg2  = (const float*)d_in[39];
    const float* vbt2 = (const float*)d_in[40];
    const float* vWo  = (const float*)d_in[41];
    const float* vbo  = (const float*)d_in[42];

    float* hsage   = (float*)d_ws;                                    // B*T*64 f32
    float* embLast = hsage + (size_t)BB * TT * SAGE_H;                // B*256 f32
    unsigned short* wt = (unsigned short*)(embLast + (size_t)BB * GAT_TOT); // [256][64] bf16
    float* statc = (float*)(wt + 256 * GH);                           // [20] f32

    setup_kernel<<<1, 256, 0, stream>>>(coopW, confW, projW, projB, wt, statc);

    gat_sage_kernel<<<BB * TT, 256, 0, stream>>>(
        selfF, nbF, mask, projW, projB, projG, projBt,
        coopS, coopD, confS, confD, wt, statc,
        sageW, sageB, hsage, embLast);

    gru_head_kernel<<<BB, 256, 0, stream>>>(
        hsage, embLast,
        gfWx, gfWh, gfbx, gfbh, gbWx, gbWh, gbbx, gbbh,
        pW1, pb1, pg1, pbt1, pW2, pb2, pg2, pbt2, pWo, pbo,
        vW1, vb1, vg1, vbt1, vW2, vb2, vg2, vbt2, vWo, vbo,
        (float*)d_out);
}